// Round 1
// baseline (1882.924 us; speedup 1.0000x reference)
//
#include <hip/hip_runtime.h>

// GAM forward: 64 independent per-feature MLPs 1->16->16->16->1 (ELU), then
// pred = out @ Wp + bp.
// Kernel A computes out (N,64); kernel B computes pred (N,) from out.
// All fp32 (no fp32 MFMA on CDNA4 -> vector ALU; ~4.6 GFLOP => ~29us floor).

#define BLK 256
#define FG 8        // features per block
#define SPT 2       // samples per thread
#define DTOT 64
#define HID 16

__device__ __forceinline__ float elu_f(float v) {
    return v > 0.0f ? v : (__expf(v) - 1.0f);
}

// dot of 16-elem register array h with 16-elem register array w, ILP-4.
__device__ __forceinline__ float dot16(const float* h, const float* w) {
    float a0 = h[0] * w[0];
    float a1 = h[4] * w[4];
    float a2 = h[8] * w[8];
    float a3 = h[12] * w[12];
    a0 = fmaf(h[1], w[1], a0);
    a1 = fmaf(h[5], w[5], a1);
    a2 = fmaf(h[9], w[9], a2);
    a3 = fmaf(h[13], w[13], a3);
    a0 = fmaf(h[2], w[2], a0);
    a1 = fmaf(h[6], w[6], a1);
    a2 = fmaf(h[10], w[10], a2);
    a3 = fmaf(h[14], w[14], a3);
    a0 = fmaf(h[3], w[3], a0);
    a1 = fmaf(h[7], w[7], a1);
    a2 = fmaf(h[11], w[11], a2);
    a3 = fmaf(h[15], w[15], a3);
    return (a0 + a1) + (a2 + a3);
}

__device__ __forceinline__ void lds_row16(float* dst, const float* src) {
    // src is 16B-aligned LDS; 4x ds_read_b128 broadcast (same addr all lanes)
    *(float4*)&dst[0]  = *(const float4*)&src[0];
    *(float4*)&dst[4]  = *(const float4*)&src[4];
    *(float4*)&dst[8]  = *(const float4*)&src[8];
    *(float4*)&dst[12] = *(const float4*)&src[12];
}

__global__ __launch_bounds__(BLK, 4) void gam_main(
    const float* __restrict__ x, const float* __restrict__ W1,
    const float* __restrict__ W2, const float* __restrict__ W3,
    const float* __restrict__ W4, float* __restrict__ out, int nsamp)
{
    // Weights for this block's FG features, W2/W3 stored transposed:
    // w2s[dd][j][i] = W2[d*16+i][d*16+j]  (i contiguous -> b128 column reads)
    __shared__ float w1s[FG][16];
    __shared__ float w2s[FG][16][16];
    __shared__ float w3s[FG][16][16];
    __shared__ float w4s[FG][16];

    const int tid = threadIdx.x;
    const int g = blockIdx.x & 7;        // feature group
    const int chunk = blockIdx.x >> 3;   // sample chunk
    const int d0 = g * FG;

    // ---- stage weights ----
    if (tid < 128) {
        int dd = tid >> 4, j = tid & 15;
        int d = d0 + dd;
        w1s[dd][j] = W1[d * 1024 + d * 16 + j];
    } else {
        int t = tid - 128;
        int dd = t >> 4, i = t & 15;
        int d = d0 + dd;
        w4s[dd][i] = W4[(d * 16 + i) * 64 + d];
    }
    for (int idx = tid; idx < FG * 256; idx += BLK) {
        int dd = idx >> 8, r = idx & 255;
        int i = r >> 4, j = r & 15;   // j fast -> coalesced global reads
        int d = d0 + dd;
        size_t base = (size_t)(d * 16 + i) * 1024 + d * 16 + j;
        w2s[dd][j][i] = W2[base];
        w3s[dd][j][i] = W3[base];
    }
    __syncthreads();

    const int s0 = chunk * (BLK * SPT) + tid;
    const int s1 = s0 + BLK;
    if (s1 >= nsamp && s0 >= nsamp) return;

    // feature loop kept ROLLED (body ~12KB; full unroll would blow I$)
    for (int dd = 0; dd < FG; ++dd) {
        const int d = d0 + dd;
        const float xv0 = x[(size_t)s0 * DTOT + d];
        const float xv1 = x[(size_t)s1 * DTOT + d];

        float ha[16], hb[16];   // h1 then h3
        float ga[16], gb[16];   // h2

        // layer 1: h1 = elu(x * w1)
        {
            float wr[16];
            lds_row16(wr, &w1s[dd][0]);
#pragma unroll
            for (int j = 0; j < 16; ++j) {
                ha[j] = elu_f(xv0 * wr[j]);
                hb[j] = elu_f(xv1 * wr[j]);
            }
        }
        // layer 2: h2 = elu(h1 @ W2blk)
#pragma unroll
        for (int j = 0; j < 16; ++j) {
            float wr[16];
            lds_row16(wr, &w2s[dd][j][0]);
            ga[j] = elu_f(dot16(ha, wr));
            gb[j] = elu_f(dot16(hb, wr));
        }
        // layer 3: h3 = elu(h2 @ W3blk)  (reuse ha/hb)
#pragma unroll
        for (int j = 0; j < 16; ++j) {
            float wr[16];
            lds_row16(wr, &w3s[dd][j][0]);
            ha[j] = elu_f(dot16(ga, wr));
            hb[j] = elu_f(dot16(gb, wr));
        }
        // layer 4: out = h3 . w4
        {
            float wr[16];
            lds_row16(wr, &w4s[dd][0]);
            float o0 = dot16(ha, wr);
            float o1 = dot16(hb, wr);
            out[(size_t)s0 * DTOT + d] = o0;
            out[(size_t)s1 * DTOT + d] = o1;
        }
    }
}

// pred[s] = bp + sum_d out[s][d] * Wp[d]
// One wave handles 4 samples: 16 lanes/sample, each lane a float4 of the row.
__global__ __launch_bounds__(BLK) void gam_pred(
    const float* __restrict__ out, const float* __restrict__ Wp,
    const float* __restrict__ bp, float* __restrict__ pred, int nsamp)
{
    int gid = blockIdx.x * BLK + threadIdx.x;
    int wave = gid >> 6, lane = gid & 63;
    int sub = lane >> 4, li = lane & 15;
    int s = wave * 4 + sub;
    if (s >= nsamp) return;
    float4 wv = ((const float4*)Wp)[li];
    float4 v = ((const float4*)(out + (size_t)s * DTOT))[li];
    float p = v.x * wv.x + v.y * wv.y + v.z * wv.z + v.w * wv.w;
    p += __shfl_xor(p, 1);
    p += __shfl_xor(p, 2);
    p += __shfl_xor(p, 4);
    p += __shfl_xor(p, 8);
    if (li == 0) pred[s] = p + bp[0];
}

extern "C" void kernel_launch(void* const* d_in, const int* in_sizes, int n_in,
                              void* d_out, int out_size, void* d_ws, size_t ws_size,
                              hipStream_t stream) {
    const float* x  = (const float*)d_in[0];
    const float* W1 = (const float*)d_in[1];
    const float* W2 = (const float*)d_in[2];
    const float* W3 = (const float*)d_in[3];
    const float* W4 = (const float*)d_in[4];
    const float* Wp = (const float*)d_in[5];
    const float* bp = (const float*)d_in[6];

    const int nsamp = in_sizes[0] / DTOT;   // 65536
    float* pred = (float*)d_out;            // (N,1) first
    float* outm = pred + nsamp;             // (N,64) second

    // Kernel A: (nsamp / (256*2)) sample chunks x 8 feature groups
    int chunks = nsamp / (BLK * SPT);
    gam_main<<<dim3(chunks * 8), dim3(BLK), 0, stream>>>(x, W1, W2, W3, W4, outm, nsamp);

    // Kernel B: nsamp/4 waves, 64 threads each
    int nthreads = (nsamp / 4) * 64;
    gam_pred<<<dim3((nthreads + BLK - 1) / BLK), dim3(BLK), 0, stream>>>(outm, Wp, bp, pred, nsamp);
}

// Round 2
// 1836.572 us; speedup vs baseline: 1.0252x; 1.0252x over previous
//
#include <hip/hip_runtime.h>

// GAM forward: 64 independent per-feature MLPs 1->16->16->16->1 (ELU), then
// pred = out @ Wp + bp.
// R1 lesson: row-major (N,64) access with lane=sample is 256B-stride across
// lanes -> 200x HBM amplification (partial-line RMW across 8 XCDs).
// Fix: work transposed. xt/ot are (64,N) in d_ws; every global access is
// lane-contiguous. Two tiny tile-transpose kernels convert at the edges.

#define BLK 256
#define FG 8        // features per block
#define SPT 2       // samples per thread
#define DTOT 64

__device__ __forceinline__ float elu_f(float v) {
    return v > 0.0f ? v : (__expf(v) - 1.0f);
}

// dot of 16-elem register array h with 16-elem register array w, ILP-4.
__device__ __forceinline__ float dot16(const float* h, const float* w) {
    float a0 = h[0] * w[0];
    float a1 = h[4] * w[4];
    float a2 = h[8] * w[8];
    float a3 = h[12] * w[12];
    a0 = fmaf(h[1], w[1], a0);
    a1 = fmaf(h[5], w[5], a1);
    a2 = fmaf(h[9], w[9], a2);
    a3 = fmaf(h[13], w[13], a3);
    a0 = fmaf(h[2], w[2], a0);
    a1 = fmaf(h[6], w[6], a1);
    a2 = fmaf(h[10], w[10], a2);
    a3 = fmaf(h[14], w[14], a3);
    a0 = fmaf(h[3], w[3], a0);
    a1 = fmaf(h[7], w[7], a1);
    a2 = fmaf(h[11], w[11], a2);
    a3 = fmaf(h[15], w[15], a3);
    return (a0 + a1) + (a2 + a3);
}

__device__ __forceinline__ void lds_row16(float* dst, const float* src) {
    // src is 16B-aligned LDS; 4x ds_read_b128 broadcast (same addr all lanes)
    *(float4*)&dst[0]  = *(const float4*)&src[0];
    *(float4*)&dst[4]  = *(const float4*)&src[4];
    *(float4*)&dst[8]  = *(const float4*)&src[8];
    *(float4*)&dst[12] = *(const float4*)&src[12];
}

// Stage this block's FG features' live weight blocks into LDS.
// w2s/w3s transposed: w2s[dd][j][i] = W2[d*16+i][d*16+j] (i contiguous).
__device__ __forceinline__ void stage_weights(
    int tid, int d0,
    const float* __restrict__ W1, const float* __restrict__ W2,
    const float* __restrict__ W3, const float* __restrict__ W4,
    float (*w1s)[16], float (*w2s)[16][16], float (*w3s)[16][16], float (*w4s)[16])
{
    if (tid < 128) {
        int dd = tid >> 4, j = tid & 15;
        int d = d0 + dd;
        w1s[dd][j] = W1[d * 1024 + d * 16 + j];
    } else {
        int t = tid - 128;
        int dd = t >> 4, i = t & 15;
        int d = d0 + dd;
        w4s[dd][i] = W4[(d * 16 + i) * 64 + d];
    }
    for (int idx = tid; idx < FG * 256; idx += BLK) {
        int dd = idx >> 8, r = idx & 255;
        int i = r >> 4, j = r & 15;   // j fast -> coalesced global reads
        int d = d0 + dd;
        size_t base = (size_t)(d * 16 + i) * 1024 + d * 16 + j;
        w2s[dd][j][i] = W2[base];
        w3s[dd][j][i] = W3[base];
    }
}

// ---------------- fast path: transposed domain ----------------

// x (N,64) -> xt (64,N). 64x64 tiles via LDS (pad 65 -> conflict-free).
__global__ __launch_bounds__(256) void transpose_in(
    const float* __restrict__ x, float* __restrict__ xt, int nsamp)
{
    __shared__ float t[64][65];
    const int s0 = blockIdx.x * 64;
    const int c = threadIdx.x & 63;
    const int r0 = threadIdx.x >> 6;
    for (int i = r0; i < 64; i += 4)
        t[i][c] = x[(size_t)(s0 + i) * DTOT + c];
    __syncthreads();
    for (int d = r0; d < 64; d += 4)
        xt[(size_t)d * nsamp + s0 + c] = t[c][d];
}

// ot (64,N) -> out (N,64).
__global__ __launch_bounds__(256) void transpose_out(
    const float* __restrict__ ot, float* __restrict__ out, int nsamp)
{
    __shared__ float t[64][65];
    const int s0 = blockIdx.x * 64;
    const int c = threadIdx.x & 63;
    const int r0 = threadIdx.x >> 6;
    for (int d = r0; d < 64; d += 4)
        t[d][c] = ot[(size_t)d * nsamp + s0 + c];
    __syncthreads();
    for (int i = r0; i < 64; i += 4)
        out[(size_t)(s0 + i) * DTOT + c] = t[c][i];
}

__global__ __launch_bounds__(BLK, 4) void gam_main_t(
    const float* __restrict__ xt, const float* __restrict__ W1,
    const float* __restrict__ W2, const float* __restrict__ W3,
    const float* __restrict__ W4, float* __restrict__ ot, int nsamp)
{
    __shared__ float w1s[FG][16];
    __shared__ float w2s[FG][16][16];
    __shared__ float w3s[FG][16][16];
    __shared__ float w4s[FG][16];

    const int tid = threadIdx.x;
    const int g = blockIdx.x & 7;        // feature group
    const int chunk = blockIdx.x >> 3;   // sample chunk
    const int d0 = g * FG;

    stage_weights(tid, d0, W1, W2, W3, W4, w1s, w2s, w3s, w4s);
    __syncthreads();

    const int s0 = chunk * (BLK * SPT) + tid;
    const int s1 = s0 + BLK;
    if (s0 >= nsamp) return;

    // feature loop kept ROLLED (body ~12KB; full unroll would blow I$)
    for (int dd = 0; dd < FG; ++dd) {
        const int d = d0 + dd;
        const size_t rowb = (size_t)d * nsamp;
        const float xv0 = xt[rowb + s0];            // lane-contiguous
        const float xv1 = xt[rowb + s1];

        float ha[16], hb[16];   // h1 then h3
        float ga[16], gb[16];   // h2

        // layer 1: h1 = elu(x * w1)
        {
            float wr[16];
            lds_row16(wr, &w1s[dd][0]);
#pragma unroll
            for (int j = 0; j < 16; ++j) {
                ha[j] = elu_f(xv0 * wr[j]);
                hb[j] = elu_f(xv1 * wr[j]);
            }
        }
        // layer 2: h2 = elu(h1 @ W2blk)
#pragma unroll
        for (int j = 0; j < 16; ++j) {
            float wr[16];
            lds_row16(wr, &w2s[dd][j][0]);
            ga[j] = elu_f(dot16(ha, wr));
            gb[j] = elu_f(dot16(hb, wr));
        }
        // layer 3: h3 = elu(h2 @ W3blk)  (reuse ha/hb)
#pragma unroll
        for (int j = 0; j < 16; ++j) {
            float wr[16];
            lds_row16(wr, &w3s[dd][j][0]);
            ha[j] = elu_f(dot16(ga, wr));
            hb[j] = elu_f(dot16(gb, wr));
        }
        // layer 4: out = h3 . w4
        {
            float wr[16];
            lds_row16(wr, &w4s[dd][0]);
            ot[rowb + s0] = dot16(ha, wr);          // lane-contiguous
            ot[rowb + s1] = dot16(hb, wr);
        }
    }
}

// pred[s] = bp + sum_d ot[d][s] * Wp[d]; all loads lane-contiguous.
__global__ __launch_bounds__(256) void gam_pred_t(
    const float* __restrict__ ot, const float* __restrict__ Wp,
    const float* __restrict__ bp, float* __restrict__ pred, int nsamp)
{
    const int s = blockIdx.x * 256 + threadIdx.x;
    if (s >= nsamp) return;
    float p = bp[0];
#pragma unroll
    for (int d = 0; d < DTOT; ++d)
        p = fmaf(ot[(size_t)d * nsamp + s], Wp[d], p);
    pred[s] = p;
}

// ---------------- fallback path (ws too small): R0 kernels ----------------

__global__ __launch_bounds__(BLK, 4) void gam_main_direct(
    const float* __restrict__ x, const float* __restrict__ W1,
    const float* __restrict__ W2, const float* __restrict__ W3,
    const float* __restrict__ W4, float* __restrict__ out, int nsamp)
{
    __shared__ float w1s[FG][16];
    __shared__ float w2s[FG][16][16];
    __shared__ float w3s[FG][16][16];
    __shared__ float w4s[FG][16];

    const int tid = threadIdx.x;
    const int g = blockIdx.x & 7;
    const int chunk = blockIdx.x >> 3;
    const int d0 = g * FG;

    stage_weights(tid, d0, W1, W2, W3, W4, w1s, w2s, w3s, w4s);
    __syncthreads();

    const int s0 = chunk * (BLK * SPT) + tid;
    const int s1 = s0 + BLK;
    if (s0 >= nsamp) return;

    for (int dd = 0; dd < FG; ++dd) {
        const int d = d0 + dd;
        const float xv0 = x[(size_t)s0 * DTOT + d];
        const float xv1 = x[(size_t)s1 * DTOT + d];
        float ha[16], hb[16], ga[16], gb[16];
        {
            float wr[16];
            lds_row16(wr, &w1s[dd][0]);
#pragma unroll
            for (int j = 0; j < 16; ++j) {
                ha[j] = elu_f(xv0 * wr[j]);
                hb[j] = elu_f(xv1 * wr[j]);
            }
        }
#pragma unroll
        for (int j = 0; j < 16; ++j) {
            float wr[16];
            lds_row16(wr, &w2s[dd][j][0]);
            ga[j] = elu_f(dot16(ha, wr));
            gb[j] = elu_f(dot16(hb, wr));
        }
#pragma unroll
        for (int j = 0; j < 16; ++j) {
            float wr[16];
            lds_row16(wr, &w3s[dd][j][0]);
            ha[j] = elu_f(dot16(ga, wr));
            hb[j] = elu_f(dot16(gb, wr));
        }
        {
            float wr[16];
            lds_row16(wr, &w4s[dd][0]);
            out[(size_t)s0 * DTOT + d] = dot16(ha, wr);
            out[(size_t)s1 * DTOT + d] = dot16(hb, wr);
        }
    }
}

__global__ __launch_bounds__(BLK) void gam_pred_direct(
    const float* __restrict__ out, const float* __restrict__ Wp,
    const float* __restrict__ bp, float* __restrict__ pred, int nsamp)
{
    int gid = blockIdx.x * BLK + threadIdx.x;
    int wave = gid >> 6, lane = gid & 63;
    int sub = lane >> 4, li = lane & 15;
    int s = wave * 4 + sub;
    if (s >= nsamp) return;
    float4 wv = ((const float4*)Wp)[li];
    float4 v = ((const float4*)(out + (size_t)s * DTOT))[li];
    float p = v.x * wv.x + v.y * wv.y + v.z * wv.z + v.w * wv.w;
    p += __shfl_xor(p, 1);
    p += __shfl_xor(p, 2);
    p += __shfl_xor(p, 4);
    p += __shfl_xor(p, 8);
    if (li == 0) pred[s] = p + bp[0];
}

extern "C" void kernel_launch(void* const* d_in, const int* in_sizes, int n_in,
                              void* d_out, int out_size, void* d_ws, size_t ws_size,
                              hipStream_t stream) {
    const float* x  = (const float*)d_in[0];
    const float* W1 = (const float*)d_in[1];
    const float* W2 = (const float*)d_in[2];
    const float* W3 = (const float*)d_in[3];
    const float* W4 = (const float*)d_in[4];
    const float* Wp = (const float*)d_in[5];
    const float* bp = (const float*)d_in[6];

    const int nsamp = in_sizes[0] / DTOT;   // 65536
    float* pred = (float*)d_out;            // (N,1) first
    float* outm = pred + nsamp;             // (N,64) second

    const size_t need = (size_t)2 * nsamp * DTOT * sizeof(float);
    if (ws_size >= need) {
        float* xt = (float*)d_ws;
        float* ot = xt + (size_t)nsamp * DTOT;
        transpose_in<<<dim3(nsamp / 64), dim3(256), 0, stream>>>(x, xt, nsamp);
        gam_main_t<<<dim3((nsamp / (BLK * SPT)) * 8), dim3(BLK), 0, stream>>>(
            xt, W1, W2, W3, W4, ot, nsamp);
        transpose_out<<<dim3(nsamp / 64), dim3(256), 0, stream>>>(ot, outm, nsamp);
        gam_pred_t<<<dim3(nsamp / 256), dim3(256), 0, stream>>>(ot, Wp, bp, pred, nsamp);
    } else {
        int chunks = nsamp / (BLK * SPT);
        gam_main_direct<<<dim3(chunks * 8), dim3(BLK), 0, stream>>>(
            x, W1, W2, W3, W4, outm, nsamp);
        int nthreads = (nsamp / 4) * 64;
        gam_pred_direct<<<dim3((nthreads + BLK - 1) / BLK), dim3(BLK), 0, stream>>>(
            outm, Wp, bp, pred, nsamp);
    }
}

// Round 5
// 94.919 us; speedup vs baseline: 19.8372x; 19.3488x over previous
//
#include <hip/hip_runtime.h>

// GAM forward: 64 per-feature MLPs 1->16->16->16->1 (ELU), pred = out@Wp+bp.
// R1 lesson: row-major lane=sample global access -> partial-line RMW blowup.
// R2 lesson: local float arrays accessed through float*/float4* casts defeat
//   SROA -> 4.5GB of scratch traffic (VGPR_Count=64 was the tell). Fix: ALL
//   per-thread state is named float4 variables; layers iterate over the INPUT
//   index so weights load as transient float4 broadcasts in natural layout.
// R3/R4: infra failures (UnresponsiveContainer) — resubmitting unchanged.

#define BLK 256
#define FG 8        // features per block
#define SPT 2       // samples per thread
#define DTOT 64

__device__ __forceinline__ float getc(float4 v, int i) {
    switch (i & 3) {
        case 0: return v.x;
        case 1: return v.y;
        case 2: return v.z;
        default: return v.w;
    }
}
// compile-time-folded 16-way select (i is a constant under #pragma unroll)
#define GET16(h0, h1, h2, h3, i) \
    getc((i) < 4 ? (h0) : (i) < 8 ? (h1) : (i) < 12 ? (h2) : (h3), (i))

__device__ __forceinline__ float4 mul4(float s, float4 w) {
    float4 r;
    r.x = s * w.x; r.y = s * w.y; r.z = s * w.z; r.w = s * w.w;
    return r;
}
__device__ __forceinline__ float4 fma4(float s, float4 w, float4 a) {
    a.x = fmaf(s, w.x, a.x); a.y = fmaf(s, w.y, a.y);
    a.z = fmaf(s, w.z, a.z); a.w = fmaf(s, w.w, a.w);
    return a;
}
__device__ __forceinline__ float elu_f(float v) {
    return v > 0.0f ? v : (__expf(v) - 1.0f);
}
__device__ __forceinline__ float4 elu4(float4 v) {
    float4 r;
    r.x = elu_f(v.x); r.y = elu_f(v.y); r.z = elu_f(v.z); r.w = elu_f(v.w);
    return r;
}
__device__ __forceinline__ float dot4(float4 a, float4 b) {
    return fmaf(a.x, b.x, fmaf(a.y, b.y, fmaf(a.z, b.z, a.w * b.w)));
}
__device__ __forceinline__ float4 zero4() {
    float4 r; r.x = 0.f; r.y = 0.f; r.z = 0.f; r.w = 0.f; return r;
}

// Stage FG features' live weight blocks into LDS, NATURAL [i][j] layout
// (j contiguous): w2s[dd][i][j] = W2[(d*16+i)*1024 + d*16 + j].
__device__ __forceinline__ void stage_weights(
    int tid, int d0,
    const float* __restrict__ W1, const float* __restrict__ W2,
    const float* __restrict__ W3, const float* __restrict__ W4,
    float (*w1s)[16], float (*w2s)[16][16], float (*w3s)[16][16], float (*w4s)[16])
{
    if (tid < 128) {
        int dd = tid >> 4, j = tid & 15;
        int d = d0 + dd;
        w1s[dd][j] = W1[d * 1024 + d * 16 + j];
    } else {
        int t = tid - 128;
        int dd = t >> 4, i = t & 15;
        int d = d0 + dd;
        w4s[dd][i] = W4[(d * 16 + i) * 64 + d];
    }
    for (int idx = tid; idx < FG * 256; idx += BLK) {
        int dd = idx >> 8, r = idx & 255;
        int i = r >> 4, j = r & 15;   // j fast -> coalesced
        int d = d0 + dd;
        size_t base = (size_t)(d * 16 + i) * 1024 + d * 16 + j;
        w2s[dd][i][j] = W2[base];
        w3s[dd][i][j] = W3[base];
    }
}

// Full 16->16 layer for 2 samples: acc_j = sum_i h_i * W[i][j], then ELU.
// ws = &w?s[dd][0][0]. All state in named float4s -> pure registers.
#define LAYER16(ws)                                                        \
    {                                                                      \
        float4 a0 = zero4(), a1 = zero4(), a2 = zero4(), a3 = zero4();     \
        float4 b0 = zero4(), b1 = zero4(), b2 = zero4(), b3 = zero4();     \
        _Pragma("unroll")                                                  \
        for (int i = 0; i < 16; ++i) {                                     \
            const float hai = GET16(ha0, ha1, ha2, ha3, i);                \
            const float hbi = GET16(hb0, hb1, hb2, hb3, i);                \
            const float4* wp = (const float4*)((ws) + i * 16);             \
            const float4 q0 = wp[0], q1 = wp[1], q2 = wp[2], q3 = wp[3];   \
            a0 = fma4(hai, q0, a0); a1 = fma4(hai, q1, a1);                \
            a2 = fma4(hai, q2, a2); a3 = fma4(hai, q3, a3);                \
            b0 = fma4(hbi, q0, b0); b1 = fma4(hbi, q1, b1);                \
            b2 = fma4(hbi, q2, b2); b3 = fma4(hbi, q3, b3);                \
        }                                                                  \
        ha0 = elu4(a0); ha1 = elu4(a1); ha2 = elu4(a2); ha3 = elu4(a3);    \
        hb0 = elu4(b0); hb1 = elu4(b1); hb2 = elu4(b2); hb3 = elu4(b3);    \
    }

// ---------------- fast path: transposed domain ----------------

// x (N,64) -> xt (64,N). 64x64 tiles via LDS (pad 65 -> conflict-free).
__global__ __launch_bounds__(256) void transpose_in(
    const float* __restrict__ x, float* __restrict__ xt, int nsamp)
{
    __shared__ float t[64][65];
    const int s0 = blockIdx.x * 64;
    const int c = threadIdx.x & 63;
    const int r0 = threadIdx.x >> 6;
    for (int i = r0; i < 64; i += 4)
        t[i][c] = x[(size_t)(s0 + i) * DTOT + c];
    __syncthreads();
    for (int d = r0; d < 64; d += 4)
        xt[(size_t)d * nsamp + s0 + c] = t[c][d];
}

__global__ __launch_bounds__(BLK, 4) void gam_main_t(
    const float* __restrict__ xt, const float* __restrict__ W1,
    const float* __restrict__ W2, const float* __restrict__ W3,
    const float* __restrict__ W4, float* __restrict__ ot, int nsamp)
{
    __shared__ float w1s[FG][16];
    __shared__ float w2s[FG][16][16];
    __shared__ float w3s[FG][16][16];
    __shared__ float w4s[FG][16];

    const int tid = threadIdx.x;
    const int g = blockIdx.x & 7;        // feature group
    const int chunk = blockIdx.x >> 3;   // sample chunk
    const int d0 = g * FG;

    stage_weights(tid, d0, W1, W2, W3, W4, w1s, w2s, w3s, w4s);
    __syncthreads();

    const int s0 = chunk * (BLK * SPT) + tid;
    const int s1 = s0 + BLK;
    if (s0 >= nsamp) return;

    for (int dd = 0; dd < FG; ++dd) {   // rolled: body ~7KB, fits I$
        const int d = d0 + dd;
        const size_t rowb = (size_t)d * nsamp;
        const float xv0 = xt[rowb + s0];            // lane-contiguous
        const float xv1 = xt[rowb + s1];

        // layer 1
        const float4* w1p = (const float4*)&w1s[dd][0];
        const float4 u0 = w1p[0], u1 = w1p[1], u2 = w1p[2], u3 = w1p[3];
        float4 ha0 = elu4(mul4(xv0, u0)), ha1 = elu4(mul4(xv0, u1));
        float4 ha2 = elu4(mul4(xv0, u2)), ha3 = elu4(mul4(xv0, u3));
        float4 hb0 = elu4(mul4(xv1, u0)), hb1 = elu4(mul4(xv1, u1));
        float4 hb2 = elu4(mul4(xv1, u2)), hb3 = elu4(mul4(xv1, u3));

        // layers 2,3
        LAYER16(&w2s[dd][0][0]);
        LAYER16(&w3s[dd][0][0]);

        // layer 4: scalar out per sample
        const float4* w4p = (const float4*)&w4s[dd][0];
        const float4 q0 = w4p[0], q1 = w4p[1], q2 = w4p[2], q3 = w4p[3];
        const float oa = (dot4(ha0, q0) + dot4(ha1, q1)) +
                         (dot4(ha2, q2) + dot4(ha3, q3));
        const float ob = (dot4(hb0, q0) + dot4(hb1, q1)) +
                         (dot4(hb2, q2) + dot4(hb3, q3));
        ot[rowb + s0] = oa;                          // lane-contiguous
        ot[rowb + s1] = ob;
    }
}

// ot (64,N) -> out (N,64) AND pred[s] = bp + sum_d ot[d][s]*Wp[d], fused.
__global__ __launch_bounds__(256) void finish(
    const float* __restrict__ ot, const float* __restrict__ Wp,
    const float* __restrict__ bp, float* __restrict__ out,
    float* __restrict__ pred, int nsamp)
{
    __shared__ float t[64][65];
    __shared__ float wps[64];
    const int s0 = blockIdx.x * 64;
    const int c = threadIdx.x & 63;
    const int r0 = threadIdx.x >> 6;
    if (threadIdx.x < 64) wps[threadIdx.x] = Wp[threadIdx.x];
    for (int d = r0; d < 64; d += 4)
        t[d][c] = ot[(size_t)d * nsamp + s0 + c];
    __syncthreads();
    for (int i = r0; i < 64; i += 4)
        out[(size_t)(s0 + i) * DTOT + c] = t[c][i];   // full 256B lines
    if (r0 == 0) {
        float p = bp[0];
#pragma unroll
        for (int d = 0; d < 64; ++d)
            p = fmaf(t[d][c], wps[d], p);   // banks (d+c)%32: conflict-free
        pred[s0 + c] = p;
    }
}

// ---------------- fallback (ws too small; same math, strided I/O) ---------

__global__ __launch_bounds__(BLK, 4) void gam_main_direct(
    const float* __restrict__ x, const float* __restrict__ W1,
    const float* __restrict__ W2, const float* __restrict__ W3,
    const float* __restrict__ W4, float* __restrict__ out, int nsamp)
{
    __shared__ float w1s[FG][16];
    __shared__ float w2s[FG][16][16];
    __shared__ float w3s[FG][16][16];
    __shared__ float w4s[FG][16];

    const int tid = threadIdx.x;
    const int g = blockIdx.x & 7;
    const int chunk = blockIdx.x >> 3;
    const int d0 = g * FG;

    stage_weights(tid, d0, W1, W2, W3, W4, w1s, w2s, w3s, w4s);
    __syncthreads();

    const int s0 = chunk * (BLK * SPT) + tid;
    const int s1 = s0 + BLK;
    if (s0 >= nsamp) return;

    for (int dd = 0; dd < FG; ++dd) {
        const int d = d0 + dd;
        const float xv0 = x[(size_t)s0 * DTOT + d];
        const float xv1 = x[(size_t)s1 * DTOT + d];

        const float4* w1p = (const float4*)&w1s[dd][0];
        const float4 u0 = w1p[0], u1 = w1p[1], u2 = w1p[2], u3 = w1p[3];
        float4 ha0 = elu4(mul4(xv0, u0)), ha1 = elu4(mul4(xv0, u1));
        float4 ha2 = elu4(mul4(xv0, u2)), ha3 = elu4(mul4(xv0, u3));
        float4 hb0 = elu4(mul4(xv1, u0)), hb1 = elu4(mul4(xv1, u1));
        float4 hb2 = elu4(mul4(xv1, u2)), hb3 = elu4(mul4(xv1, u3));

        LAYER16(&w2s[dd][0][0]);
        LAYER16(&w3s[dd][0][0]);

        const float4* w4p = (const float4*)&w4s[dd][0];
        const float4 q0 = w4p[0], q1 = w4p[1], q2 = w4p[2], q3 = w4p[3];
        out[(size_t)s0 * DTOT + d] = (dot4(ha0, q0) + dot4(ha1, q1)) +
                                     (dot4(ha2, q2) + dot4(ha3, q3));
        out[(size_t)s1 * DTOT + d] = (dot4(hb0, q0) + dot4(hb1, q1)) +
                                     (dot4(hb2, q2) + dot4(hb3, q3));
    }
}

__global__ __launch_bounds__(BLK) void gam_pred_direct(
    const float* __restrict__ out, const float* __restrict__ Wp,
    const float* __restrict__ bp, float* __restrict__ pred, int nsamp)
{
    int gid = blockIdx.x * BLK + threadIdx.x;
    int wave = gid >> 6, lane = gid & 63;
    int sub = lane >> 4, li = lane & 15;
    int s = wave * 4 + sub;
    if (s >= nsamp) return;
    float4 wv = ((const float4*)Wp)[li];
    float4 v = ((const float4*)(out + (size_t)s * DTOT))[li];
    float p = v.x * wv.x + v.y * wv.y + v.z * wv.z + v.w * wv.w;
    p += __shfl_xor(p, 1);
    p += __shfl_xor(p, 2);
    p += __shfl_xor(p, 4);
    p += __shfl_xor(p, 8);
    if (li == 0) pred[s] = p + bp[0];
}

extern "C" void kernel_launch(void* const* d_in, const int* in_sizes, int n_in,
                              void* d_out, int out_size, void* d_ws, size_t ws_size,
                              hipStream_t stream) {
    const float* x  = (const float*)d_in[0];
    const float* W1 = (const float*)d_in[1];
    const float* W2 = (const float*)d_in[2];
    const float* W3 = (const float*)d_in[3];
    const float* W4 = (const float*)d_in[4];
    const float* Wp = (const float*)d_in[5];
    const float* bp = (const float*)d_in[6];

    const int nsamp = in_sizes[0] / DTOT;   // 65536
    float* pred = (float*)d_out;            // (N,1) first
    float* outm = pred + nsamp;             // (N,64) second

    const size_t need = (size_t)2 * nsamp * DTOT * sizeof(float);
    if (ws_size >= need) {
        float* xt = (float*)d_ws;
        float* ot = xt + (size_t)nsamp * DTOT;
        transpose_in<<<dim3(nsamp / 64), dim3(256), 0, stream>>>(x, xt, nsamp);
        gam_main_t<<<dim3((nsamp / (BLK * SPT)) * 8), dim3(BLK), 0, stream>>>(
            xt, W1, W2, W3, W4, ot, nsamp);
        finish<<<dim3(nsamp / 64), dim3(256), 0, stream>>>(
            ot, Wp, bp, outm, pred, nsamp);
    } else {
        int chunks = nsamp / (BLK * SPT);
        gam_main_direct<<<dim3(chunks * 8), dim3(BLK), 0, stream>>>(
            x, W1, W2, W3, W4, outm, nsamp);
        int nthreads = (nsamp / 4) * 64;
        gam_pred_direct<<<dim3((nthreads + BLK - 1) / BLK), dim3(BLK), 0, stream>>>(
            outm, Wp, bp, pred, nsamp);
    }
}

// Round 6
// 91.577 us; speedup vs baseline: 20.5611x; 1.0365x over previous
//
#include <hip/hip_runtime.h>

// GAM forward: 64 per-feature MLPs 1->16->16->16->1 (ELU), pred = out@Wp+bp.
// R1: row-major lane=sample global access -> partial-line RMW blowup (250x).
// R2/R5: pointer-cast local arrays -> scratch spill (4.5GB traffic); fixed
//   with named float4 state -> 94.9us, VALUBusy 75%, hbm 25MB.
// R5 analysis: now LDS-ISSUE-bound: 17,408 ds_read_b128/CU x ~12cyc = 87us
//   == measured 88.4us. Weights are WAVE-UNIFORM -> read directly from
//   global (uniformity + __restrict__ noclobber => s_load_dwordx16 into
//   SGPRs; FMA uses SGPR operand). No LDS at all; FG=4 for 8 blocks/CU.

#define BLK 256
#define FGF 4       // features per block (fast path, no-LDS)
#define FG 8        // features per block (fallback path)
#define DTOT 64

__device__ __forceinline__ float getc(float4 v, int i) {
    switch (i & 3) {
        case 0: return v.x;
        case 1: return v.y;
        case 2: return v.z;
        default: return v.w;
    }
}
// compile-time-folded 16-way select (i is a constant under #pragma unroll)
#define GET16(h0, h1, h2, h3, i) \
    getc((i) < 4 ? (h0) : (i) < 8 ? (h1) : (i) < 12 ? (h2) : (h3), (i))

__device__ __forceinline__ float4 mul4(float s, float4 w) {
    float4 r;
    r.x = s * w.x; r.y = s * w.y; r.z = s * w.z; r.w = s * w.w;
    return r;
}
__device__ __forceinline__ float4 fma4(float s, float4 w, float4 a) {
    a.x = fmaf(s, w.x, a.x); a.y = fmaf(s, w.y, a.y);
    a.z = fmaf(s, w.z, a.z); a.w = fmaf(s, w.w, a.w);
    return a;
}
__device__ __forceinline__ float elu_f(float v) {
    return v > 0.0f ? v : (__expf(v) - 1.0f);
}
__device__ __forceinline__ float4 elu4(float4 v) {
    float4 r;
    r.x = elu_f(v.x); r.y = elu_f(v.y); r.z = elu_f(v.z); r.w = elu_f(v.w);
    return r;
}
__device__ __forceinline__ float dot4(float4 a, float4 b) {
    return fmaf(a.x, b.x, fmaf(a.y, b.y, fmaf(a.z, b.z, a.w * b.w)));
}
__device__ __forceinline__ float4 zero4() {
    float4 r; r.x = 0.f; r.y = 0.f; r.z = 0.f; r.w = 0.f; return r;
}

// Full 16->16 layer, 2 samples. wbase = uniform global pointer to the 16x16
// block's row 0 (row stride 1024 floats). Loads are wave-uniform 64B rows ->
// SMEM s_load; accumulation order identical to R5 kernel (absmax-stable).
#define LAYER16G(wbase)                                                     \
    {                                                                       \
        float4 a0 = zero4(), a1 = zero4(), a2 = zero4(), a3 = zero4();      \
        float4 b0 = zero4(), b1 = zero4(), b2 = zero4(), b3 = zero4();      \
        _Pragma("unroll")                                                   \
        for (int i = 0; i < 16; ++i) {                                      \
            const float hai = GET16(ha0, ha1, ha2, ha3, i);                 \
            const float hbi = GET16(hb0, hb1, hb2, hb3, i);                 \
            const float4* wp = (const float4*)((wbase) + (size_t)i * 1024); \
            const float4 q0 = wp[0], q1 = wp[1], q2 = wp[2], q3 = wp[3];    \
            a0 = fma4(hai, q0, a0); a1 = fma4(hai, q1, a1);                 \
            a2 = fma4(hai, q2, a2); a3 = fma4(hai, q3, a3);                 \
            b0 = fma4(hbi, q0, b0); b1 = fma4(hbi, q1, b1);                 \
            b2 = fma4(hbi, q2, b2); b3 = fma4(hbi, q3, b3);                 \
        }                                                                   \
        ha0 = elu4(a0); ha1 = elu4(a1); ha2 = elu4(a2); ha3 = elu4(a3);     \
        hb0 = elu4(b0); hb1 = elu4(b1); hb2 = elu4(b2); hb3 = elu4(b3);     \
    }

// ---------------- fast path: transposed domain, SMEM weights --------------

// x (N,64) -> xt (64,N). 64x64 tiles via LDS (pad 65 -> conflict-free).
__global__ __launch_bounds__(256) void transpose_in(
    const float* __restrict__ x, float* __restrict__ xt, int nsamp)
{
    __shared__ float t[64][65];
    const int s0 = blockIdx.x * 64;
    const int c = threadIdx.x & 63;
    const int r0 = threadIdx.x >> 6;
    for (int i = r0; i < 64; i += 4)
        t[i][c] = x[(size_t)(s0 + i) * DTOT + c];
    __syncthreads();
    for (int d = r0; d < 64; d += 4)
        xt[(size_t)d * nsamp + s0 + c] = t[c][d];
}

// No LDS, no barrier. 2048 blocks (nsamp/512 chunks x 16 groups of FGF=4),
// 8 blocks/CU -> up to 32 waves/CU at <=64 VGPR.
__global__ __launch_bounds__(BLK) void gam_main_s(
    const float* __restrict__ xt, const float* __restrict__ W1,
    const float* __restrict__ W2, const float* __restrict__ W3,
    const float* __restrict__ W4, float* __restrict__ ot, int nsamp)
{
    const int tid = threadIdx.x;
    const int g = blockIdx.x & 15;       // feature group (16 groups)
    const int chunk = blockIdx.x >> 4;   // sample chunk (512 samples)
    const int d0 = g * FGF;

    const int s0 = chunk * (BLK * 2) + tid;
    const int s1 = s0 + BLK;
    if (s0 >= nsamp) return;

#pragma unroll 1
    for (int dd = 0; dd < FGF; ++dd) {   // rolled: body ~10KB, fits I$
        const int d = d0 + dd;
        const size_t rowb = (size_t)d * nsamp;
        const float xv0 = xt[rowb + s0];            // lane-contiguous VMEM
        const float xv1 = xt[rowb + s1];

        // uniform per-feature weight bases (SALU arithmetic)
        const float* w1p = W1 + (size_t)d * 1024 + d * 16;        // 16 floats
        const float* w2p = W2 + (size_t)d * 16 * 1024 + d * 16;   // 16 rows
        const float* w3p = W3 + (size_t)d * 16 * 1024 + d * 16;

        // layer 1
        const float4* u = (const float4*)w1p;
        const float4 u0 = u[0], u1 = u[1], u2 = u[2], u3 = u[3];
        float4 ha0 = elu4(mul4(xv0, u0)), ha1 = elu4(mul4(xv0, u1));
        float4 ha2 = elu4(mul4(xv0, u2)), ha3 = elu4(mul4(xv0, u3));
        float4 hb0 = elu4(mul4(xv1, u0)), hb1 = elu4(mul4(xv1, u1));
        float4 hb2 = elu4(mul4(xv1, u2)), hb3 = elu4(mul4(xv1, u3));

        // layers 2,3
        LAYER16G(w2p);
        LAYER16G(w3p);

        // layer 4: W4 column (stride 64) -> 16 uniform scalar loads
        float oa0 = 0.f, oa1 = 0.f, ob0 = 0.f, ob1 = 0.f;
#pragma unroll
        for (int i = 0; i < 16; i += 2) {
            const float wa = W4[(size_t)(d * 16 + i) * 64 + d];
            const float wb = W4[(size_t)(d * 16 + i + 1) * 64 + d];
            oa0 = fmaf(GET16(ha0, ha1, ha2, ha3, i), wa, oa0);
            ob0 = fmaf(GET16(hb0, hb1, hb2, hb3, i), wa, ob0);
            oa1 = fmaf(GET16(ha0, ha1, ha2, ha3, i + 1), wb, oa1);
            ob1 = fmaf(GET16(hb0, hb1, hb2, hb3, i + 1), wb, ob1);
        }
        ot[rowb + s0] = oa0 + oa1;                  // lane-contiguous
        ot[rowb + s1] = ob0 + ob1;
    }
}

// ot (64,N) -> out (N,64) AND pred[s] = bp + sum_d ot[d][s]*Wp[d], fused.
__global__ __launch_bounds__(256) void finish(
    const float* __restrict__ ot, const float* __restrict__ Wp,
    const float* __restrict__ bp, float* __restrict__ out,
    float* __restrict__ pred, int nsamp)
{
    __shared__ float t[64][65];
    __shared__ float wps[64];
    const int s0 = blockIdx.x * 64;
    const int c = threadIdx.x & 63;
    const int r0 = threadIdx.x >> 6;
    if (threadIdx.x < 64) wps[threadIdx.x] = Wp[threadIdx.x];
    for (int d = r0; d < 64; d += 4)
        t[d][c] = ot[(size_t)d * nsamp + s0 + c];
    __syncthreads();
    for (int i = r0; i < 64; i += 4)
        out[(size_t)(s0 + i) * DTOT + c] = t[c][i];   // full 256B lines
    if (r0 == 0) {
        float p = bp[0];
#pragma unroll
        for (int d = 0; d < 64; ++d)
            p = fmaf(t[d][c], wps[d], p);   // banks (d+c)%32: conflict-free
        pred[s0 + c] = p;
    }
}

// ---------------- fallback (ws too small; LDS-staged, strided I/O) --------

__device__ __forceinline__ void stage_weights(
    int tid, int d0,
    const float* __restrict__ W1, const float* __restrict__ W2,
    const float* __restrict__ W3, const float* __restrict__ W4,
    float (*w1s)[16], float (*w2s)[16][16], float (*w3s)[16][16], float (*w4s)[16])
{
    if (tid < 128) {
        int dd = tid >> 4, j = tid & 15;
        int d = d0 + dd;
        w1s[dd][j] = W1[d * 1024 + d * 16 + j];
    } else {
        int t = tid - 128;
        int dd = t >> 4, i = t & 15;
        int d = d0 + dd;
        w4s[dd][i] = W4[(d * 16 + i) * 64 + d];
    }
    for (int idx = tid; idx < FG * 256; idx += BLK) {
        int dd = idx >> 8, r = idx & 255;
        int i = r >> 4, j = r & 15;
        int d = d0 + dd;
        size_t base = (size_t)(d * 16 + i) * 1024 + d * 16 + j;
        w2s[dd][i][j] = W2[base];
        w3s[dd][i][j] = W3[base];
    }
}

#define LAYER16L(ws)                                                       \
    {                                                                      \
        float4 a0 = zero4(), a1 = zero4(), a2 = zero4(), a3 = zero4();     \
        float4 b0 = zero4(), b1 = zero4(), b2 = zero4(), b3 = zero4();     \
        _Pragma("unroll")                                                  \
        for (int i = 0; i < 16; ++i) {                                     \
            const float hai = GET16(ha0, ha1, ha2, ha3, i);                \
            const float hbi = GET16(hb0, hb1, hb2, hb3, i);                \
            const float4* wp = (const float4*)((ws) + i * 16);             \
            const float4 q0 = wp[0], q1 = wp[1], q2 = wp[2], q3 = wp[3];   \
            a0 = fma4(hai, q0, a0); a1 = fma4(hai, q1, a1);                \
            a2 = fma4(hai, q2, a2); a3 = fma4(hai, q3, a3);                \
            b0 = fma4(hbi, q0, b0); b1 = fma4(hbi, q1, b1);                \
            b2 = fma4(hbi, q2, b2); b3 = fma4(hbi, q3, b3);                \
        }                                                                  \
        ha0 = elu4(a0); ha1 = elu4(a1); ha2 = elu4(a2); ha3 = elu4(a3);    \
        hb0 = elu4(b0); hb1 = elu4(b1); hb2 = elu4(b2); hb3 = elu4(b3);    \
    }

__global__ __launch_bounds__(BLK, 4) void gam_main_direct(
    const float* __restrict__ x, const float* __restrict__ W1,
    const float* __restrict__ W2, const float* __restrict__ W3,
    const float* __restrict__ W4, float* __restrict__ out, int nsamp)
{
    __shared__ float w1s[FG][16];
    __shared__ float w2s[FG][16][16];
    __shared__ float w3s[FG][16][16];
    __shared__ float w4s[FG][16];

    const int tid = threadIdx.x;
    const int g = blockIdx.x & 7;
    const int chunk = blockIdx.x >> 3;
    const int d0 = g * FG;

    stage_weights(tid, d0, W1, W2, W3, W4, w1s, w2s, w3s, w4s);
    __syncthreads();

    const int s0 = chunk * (BLK * 2) + tid;
    const int s1 = s0 + BLK;
    if (s0 >= nsamp) return;

    for (int dd = 0; dd < FG; ++dd) {
        const int d = d0 + dd;
        const float xv0 = x[(size_t)s0 * DTOT + d];
        const float xv1 = x[(size_t)s1 * DTOT + d];

        const float4* w1p = (const float4*)&w1s[dd][0];
        const float4 u0 = w1p[0], u1 = w1p[1], u2 = w1p[2], u3 = w1p[3];
        float4 ha0 = elu4(mul4(xv0, u0)), ha1 = elu4(mul4(xv0, u1));
        float4 ha2 = elu4(mul4(xv0, u2)), ha3 = elu4(mul4(xv0, u3));
        float4 hb0 = elu4(mul4(xv1, u0)), hb1 = elu4(mul4(xv1, u1));
        float4 hb2 = elu4(mul4(xv1, u2)), hb3 = elu4(mul4(xv1, u3));

        LAYER16L(&w2s[dd][0][0]);
        LAYER16L(&w3s[dd][0][0]);

        const float4* w4p = (const float4*)&w4s[dd][0];
        const float4 q0 = w4p[0], q1 = w4p[1], q2 = w4p[2], q3 = w4p[3];
        out[(size_t)s0 * DTOT + d] = (dot4(ha0, q0) + dot4(ha1, q1)) +
                                     (dot4(ha2, q2) + dot4(ha3, q3));
        out[(size_t)s1 * DTOT + d] = (dot4(hb0, q0) + dot4(hb1, q1)) +
                                     (dot4(hb2, q2) + dot4(hb3, q3));
    }
}

__global__ __launch_bounds__(BLK) void gam_pred_direct(
    const float* __restrict__ out, const float* __restrict__ Wp,
    const float* __restrict__ bp, float* __restrict__ pred, int nsamp)
{
    int gid = blockIdx.x * BLK + threadIdx.x;
    int wave = gid >> 6, lane = gid & 63;
    int sub = lane >> 4, li = lane & 15;
    int s = wave * 4 + sub;
    if (s >= nsamp) return;
    float4 wv = ((const float4*)Wp)[li];
    float4 v = ((const float4*)(out + (size_t)s * DTOT))[li];
    float p = v.x * wv.x + v.y * wv.y + v.z * wv.z + v.w * wv.w;
    p += __shfl_xor(p, 1);
    p += __shfl_xor(p, 2);
    p += __shfl_xor(p, 4);
    p += __shfl_xor(p, 8);
    if (li == 0) pred[s] = p + bp[0];
}

extern "C" void kernel_launch(void* const* d_in, const int* in_sizes, int n_in,
                              void* d_out, int out_size, void* d_ws, size_t ws_size,
                              hipStream_t stream) {
    const float* x  = (const float*)d_in[0];
    const float* W1 = (const float*)d_in[1];
    const float* W2 = (const float*)d_in[2];
    const float* W3 = (const float*)d_in[3];
    const float* W4 = (const float*)d_in[4];
    const float* Wp = (const float*)d_in[5];
    const float* bp = (const float*)d_in[6];

    const int nsamp = in_sizes[0] / DTOT;   // 65536
    float* pred = (float*)d_out;            // (N,1) first
    float* outm = pred + nsamp;             // (N,64) second

    const size_t need = (size_t)2 * nsamp * DTOT * sizeof(float);
    if (ws_size >= need) {
        float* xt = (float*)d_ws;
        float* ot = xt + (size_t)nsamp * DTOT;
        transpose_in<<<dim3(nsamp / 64), dim3(256), 0, stream>>>(x, xt, nsamp);
        // nsamp/512 chunks x 16 groups (FGF=4)
        gam_main_s<<<dim3((nsamp / (BLK * 2)) * 16), dim3(BLK), 0, stream>>>(
            xt, W1, W2, W3, W4, ot, nsamp);
        finish<<<dim3(nsamp / 64), dim3(256), 0, stream>>>(
            ot, Wp, bp, outm, pred, nsamp);
    } else {
        int chunks = nsamp / (BLK * 2);
        gam_main_direct<<<dim3(chunks * 8), dim3(BLK), 0, stream>>>(
            x, W1, W2, W3, W4, outm, nsamp);
        int nthreads = (nsamp / 4) * 64;
        gam_pred_direct<<<dim3((nthreads + BLK - 1) / BLK), dim3(BLK), 0, stream>>>(
            outm, Wp, bp, pred, nsamp);
    }
}